// Round 12
// baseline (180.189 us; speedup 1.0000x reference)
//
#include <hip/hip_runtime.h>
#include <stdint.h>

// Problem constants
#define B_   2
#define S_   2048
#define D_   768
#define H_   12
#define DH_  64
#define N3_  2304   // 3*D
#define M_   4096   // B*S

typedef __attribute__((ext_vector_type(8))) short    bf16x8;
typedef __attribute__((ext_vector_type(4))) float    f32x4;
typedef __attribute__((ext_vector_type(4))) int      i32x4;
typedef __attribute__((ext_vector_type(4))) unsigned short u16x4;
typedef _Float16 f16x4 __attribute__((ext_vector_type(4)));
typedef __fp16   h16x2 __attribute__((ext_vector_type(2)));   // cvt_pkrtz result type

// fold 1/sqrt(dh) * log2(e) into K at write time -> scores exit MFMA in exp2 domain
#define KSCALE 0.18033688011112042f
#define LSTRIDE (24 * S_)                 // l-buffer stride per split-K quarter
#define ONE_EL  ((size_t)24 * S_ * DH_)   // elements per Onum partial buffer

__device__ inline unsigned short f2bf(float f) {
    union { float f; unsigned u; } v; v.f = f;
    unsigned r = v.u + 0x7FFFu + ((v.u >> 16) & 1u);   // RNE
    return (unsigned short)(r >> 16);
}

// async 16B global -> LDS (DMA; LDS dest = wave-uniform base + lane*16)
__device__ inline void async_copy16(const void* g, void* l) {
    __builtin_amdgcn_global_load_lds((const __attribute__((address_space(1))) void*)g,
                                     (__attribute__((address_space(3))) void*)l, 16, 0, 0);
}

// ---------------------------------------------------------------------------
// Fused prep: x->bf16 (blocks 0..3071), w_in transpose (3072..4799),
// w_out transpose (4800..5375). Branch is block-uniform.
__global__ __launch_bounds__(256) void prep_all(
    const float* __restrict__ x, const float* __restrict__ w_in,
    const float* __restrict__ w_out,
    unsigned short* __restrict__ xb, unsigned short* __restrict__ winT,
    unsigned short* __restrict__ woutT)
{
    __shared__ unsigned short t[32][33];
    const int gid = blockIdx.x, tid = threadIdx.x;
    if (gid < 3072) {                      // cvt: 3072*256*4 = M*D elements
        int i = gid * 256 + tid;
        f32x4 v = *(const f32x4*)(x + (size_t)i * 4);
        u16x4 o;
        o.x = f2bf(v.x); o.y = f2bf(v.y); o.z = f2bf(v.z); o.w = f2bf(v.w);
        *(u16x4*)(xb + (size_t)i * 4) = o;
        return;
    }
    const float* src; unsigned short* dst; int R, C, bx, by;
    if (gid < 4800) { int b = gid - 3072; src = w_in;  dst = winT;  R = D_; C = N3_; bx = b % 72; by = b / 72; }
    else            { int b = gid - 4800; src = w_out; dst = woutT; R = D_; C = D_;  bx = b % 24; by = b / 24; }
    int c0 = bx * 32, r0 = by * 32, tx = tid & 31, ty = tid >> 5;
#pragma unroll
    for (int j = 0; j < 4; j++)
        t[ty + j * 8][tx] = f2bf(src[(size_t)(r0 + ty + j * 8) * C + c0 + tx]);
    __syncthreads();
#pragma unroll
    for (int j = 0; j < 4; j++)
        dst[(size_t)(c0 + ty + j * 8) * R + r0 + tx] = t[tx][ty + j * 8];
}

// ---------------------------------------------------------------------------
// GEMM1: QKV projection (unchanged from R11).
__global__ __launch_bounds__(256) void gemm_qkv(
    const unsigned short* __restrict__ A,
    const unsigned short* __restrict__ Bt,
    const float* __restrict__ bias,
    unsigned short* __restrict__ QK,
    unsigned short* __restrict__ Vt)
{
    __shared__ __align__(16) short Al[128 * 32];   // 8 KB
    __shared__ __align__(16) short Bl[96 * 32];    // 6 KB

    const int tid  = threadIdx.x;
    const int w    = tid >> 6;
    const int lane = tid & 63;
    const int r    = lane & 15;
    const int quad = lane >> 4;
    const int m0   = blockIdx.y * 128;
    const int n0   = blockIdx.x * 96;
    const int wm   = (w & 1) * 64;
    const int wn   = (w >> 1) * 48;
    const int K    = D_;

    f32x4 acc[4][3];
#pragma unroll
    for (int i = 0; i < 4; i++)
#pragma unroll
        for (int j = 0; j < 3; j++) acc[i][j] = f32x4{0.f, 0.f, 0.f, 0.f};

    const int c0 = tid, c1 = tid + 256;
    const size_t ga0 = (size_t)(m0 + (c0 >> 2)) * K + (c0 & 3) * 8;
    const size_t ga1 = (size_t)(m0 + (c1 >> 2)) * K + (c1 & 3) * 8;
    const size_t gb0 = (size_t)(n0 + (c0 >> 2)) * K + (c0 & 3) * 8;
    const size_t gb1 = (size_t)(n0 + (c1 >> 2)) * K + (c1 & 3) * 8;
    short* lA0 = &Al[(0 * 256 + w * 64) * 8];   // wave-uniform bases
    short* lA1 = &Al[(1 * 256 + w * 64) * 8];
    short* lB0 = &Bl[(0 * 256 + w * 64) * 8];
    short* lB1 = &Bl[(1 * 256 + w * 64) * 8];   // only waves 0,1

    for (int k0 = 0; k0 < K; k0 += 32) {
        __syncthreads();
        async_copy16(A  + ga0 + k0, lA0);
        async_copy16(A  + ga1 + k0, lA1);
        async_copy16(Bt + gb0 + k0, lB0);
        if (w < 2) async_copy16(Bt + gb1 + k0, lB1);
        __syncthreads();

        bf16x8 af[4], bf[3];
#pragma unroll
        for (int mi = 0; mi < 4; mi++)
            af[mi] = *(const bf16x8*)&Al[(wm + mi * 16 + r) * 32 + quad * 8];
#pragma unroll
        for (int ni = 0; ni < 3; ni++)
            bf[ni] = *(const bf16x8*)&Bl[(wn + ni * 16 + r) * 32 + quad * 8];
#pragma unroll
        for (int mi = 0; mi < 4; mi++)
#pragma unroll
            for (int ni = 0; ni < 3; ni++)
                acc[mi][ni] = __builtin_amdgcn_mfma_f32_16x16x32_bf16(
                    af[mi], bf[ni], acc[mi][ni], 0, 0, 0);
    }

    const size_t one = (size_t)B_ * H_ * S_ * DH_;
#pragma unroll
    for (int ni = 0; ni < 3; ni++) {
        int col  = n0 + wn + ni * 16 + r;        // 0..2303 (tiles never straddle parts)
        float bv = bias[col];
        int part = col / 768;                    // 0=q 1=k 2=v
        int cc   = col - part * 768;
        int h    = cc >> 6;
        int d    = cc & 63;
        if (part == 2) {
            // V^T direct: rows i=0..3 are consecutive s -> one 8B f16 pack
#pragma unroll
            for (int mi = 0; mi < 4; mi++) {
                int row0 = m0 + wm + mi * 16 + quad * 4;    // i=0; same b for i=0..3
                int b    = row0 >> 11;
                int s0   = row0 & 2047;
                u16x4 pk;
#pragma unroll
                for (int i = 0; i < 4; i++) {
                    union { _Float16 h; unsigned short s; } cv;
                    cv.h = (_Float16)(acc[mi][ni][i] + bv);
                    pk[i] = cv.s;
                }
                *(u16x4*)&Vt[(((size_t)(b * H_ + h)) * DH_ + d) * S_ + s0] = pk;
            }
        } else {
            float scl = (part == 1) ? KSCALE : 1.0f;
            unsigned short* dst = QK + (size_t)part * one;
#pragma unroll
            for (int mi = 0; mi < 4; mi++) {
#pragma unroll
                for (int i = 0; i < 4; i++) {
                    int row = m0 + wm + mi * 16 + quad * 4 + i;  // = b*S + s
                    int b   = row >> 11;
                    int s   = row & 2047;
                    dst[(((size_t)(b * H_ + h)) * S_ + s) * DH_ + d] =
                        f2bf((acc[mi][ni][i] + bv) * scl);
                }
            }
        }
    }
}

// ---------------------------------------------------------------------------
// GEMM2 + fused split-K combine. A-tile is built in registers from the 4
// un-normalized attention partials: a = (O0+O1+O2+O3) * 1/(l0+l1+l2+l3),
// packed to bf16 and ds_written (register-prefetched across the 2nd barrier).
// B staging stays global_load_lds DMA. Tile 64x64 -> grid 768 = 3/CU.
__global__ __launch_bounds__(256) void gemm_out(
    const unsigned short* __restrict__ On,   // 4 contiguous partials, ONE_EL apart
    const float* __restrict__ lbuf,          // 4 x LSTRIDE floats
    const unsigned short* __restrict__ Bt,
    const float* __restrict__ bias,
    float* __restrict__ Cf)
{
    __shared__ __align__(16) short Al[64 * 32];    // 4 KB
    __shared__ __align__(16) short Bl[64 * 32];    // 4 KB

    const int tid  = threadIdx.x;
    const int w    = tid >> 6;
    const int lane = tid & 63;
    const int r    = lane & 15;
    const int quad = lane >> 4;
    const int m0   = blockIdx.y * 64;
    const int n0   = blockIdx.x * 64;
    const int wm   = (w & 1) * 32;
    const int wn   = (w >> 1) * 32;
    const int K    = D_;
    const int N    = D_;

    f32x4 acc[2][2];
#pragma unroll
    for (int i = 0; i < 2; i++)
#pragma unroll
        for (int j = 0; j < 2; j++) acc[i][j] = f32x4{0.f, 0.f, 0.f, 0.f};

    // A-source addressing: row m (= b*S+s) fixed per thread; head h = k0>>6.
    const int arow = tid >> 2, d8 = (tid & 3) * 8;
    const int m = m0 + arow, bb = m >> 11, s = m & 2047;
    const size_t gb = (size_t)(n0 + (tid >> 2)) * K + (tid & 3) * 8;
    short* lB = &Bl[(w * 64) * 8];   // wave-uniform

    i32x4 a0, a1, a2, a3; float inv;
    auto pre = [&](int k0) {
        int h = k0 >> 6;
        size_t row = (size_t)(bb * H_ + h) * S_ + s;
        size_t ob  = row * 64 + (k0 & 63) + d8;
        a0 = *(const i32x4*)&On[ob];
        a1 = *(const i32x4*)&On[ob + ONE_EL];
        a2 = *(const i32x4*)&On[ob + 2 * ONE_EL];
        a3 = *(const i32x4*)&On[ob + 3 * ONE_EL];
        inv = 1.0f / (lbuf[row] + lbuf[LSTRIDE + row] +
                      lbuf[2 * LSTRIDE + row] + lbuf[3 * LSTRIDE + row]);
    };
    pre(0);

    for (int k0 = 0; k0 < K; k0 += 32) {
        __syncthreads();
        {   // combine + pack + stage A (chunk c=tid at short-offset tid*8)
            const _Float16* p0 = (const _Float16*)&a0;
            const _Float16* p1 = (const _Float16*)&a1;
            const _Float16* p2 = (const _Float16*)&a2;
            const _Float16* p3 = (const _Float16*)&a3;
            unsigned short t8[8];
#pragma unroll
            for (int j = 0; j < 8; j++)
                t8[j] = f2bf(((float)p0[j] + (float)p1[j] + (float)p2[j] + (float)p3[j]) * inv);
            *(i32x4*)&Al[tid * 8] = *(const i32x4*)t8;
        }
        async_copy16(Bt + gb + k0, lB);
        __syncthreads();
        if (k0 + 32 < K) pre(k0 + 32);

        bf16x8 af[2], bf[2];
#pragma unroll
        for (int mi = 0; mi < 2; mi++)
            af[mi] = *(const bf16x8*)&Al[(wm + mi * 16 + r) * 32 + quad * 8];
#pragma unroll
        for (int ni = 0; ni < 2; ni++)
            bf[ni] = *(const bf16x8*)&Bl[(wn + ni * 16 + r) * 32 + quad * 8];
#pragma unroll
        for (int mi = 0; mi < 2; mi++)
#pragma unroll
            for (int ni = 0; ni < 2; ni++)
                acc[mi][ni] = __builtin_amdgcn_mfma_f32_16x16x32_bf16(
                    af[mi], bf[ni], acc[mi][ni], 0, 0, 0);
    }

#pragma unroll
    for (int ni = 0; ni < 2; ni++) {
        int col  = n0 + wn + ni * 16 + r;
        float bv = bias[col];
#pragma unroll
        for (int mi = 0; mi < 2; mi++) {
#pragma unroll
            for (int i = 0; i < 4; i++) {
                int row = m0 + wm + mi * 16 + quad * 4 + i;
                Cf[(size_t)row * N + col] = acc[mi][ni][i] + bv;
            }
        }
    }
}

// ---------------------------------------------------------------------------
// Flash attention v7: S^T scheme + split-K x4 (8 kt-iters/block).
// Grid = 24*16*4 = 1536 = 6 blocks/CU -> 24 waves/CU (VGPR 76 allows 6 w/SIMD).
// Partials: Onum f16 [quarter][bh][s][64] (contiguous), l f32 [quarter][bh*s].
__global__ __launch_bounds__(256) void attn_kernel(
    const unsigned short* __restrict__ Q,
    const unsigned short* __restrict__ K,
    const unsigned short* __restrict__ Vt,
    unsigned short* __restrict__ On,
    float* __restrict__ lbuf)
{
    __shared__ __align__(16) short Kl[64 * 64];      // [key][dh], chunk^=(row&7)
    __shared__ __align__(16) short Vl[64 * 64];      // [dh][key], chunk^=(row&7)

    const int tid  = threadIdx.x;
    const int w    = tid >> 6;
    const int lane = tid & 63;
    const int r    = lane & 15;
    const int quad = lane >> 4;
    const int xk   = r & 7;
    const int bid  = blockIdx.x;
    const int bh   = bid % 24;            // head-major -> L2 locality
    const int t2   = bid / 24;            // 0..63
    const int qb   = t2 & 15;
    const int quarter = t2 >> 4;          // 0..3
    const size_t baseQK = (size_t)bh * S_ * DH_;
    const size_t baseV  = (size_t)bh * DH_ * S_;
    const int q0   = qb * 128;
    const int kt0  = quarter * 8;

    bf16x8 qf[2][2];
#pragma unroll
    for (int qt = 0; qt < 2; qt++) {
        const unsigned short* qp =
            Q + baseQK + (size_t)(q0 + w * 32 + qt * 16 + r) * DH_ + quad * 8;
        qf[qt][0] = *(const bf16x8*)(qp);
        qf[qt][1] = *(const bf16x8*)(qp + 32);
    }

    f32x4 o[2][4];
    f32x4 lacc[2];
#pragma unroll
    for (int qt = 0; qt < 2; qt++) {
        lacc[qt] = f32x4{0.f, 0.f, 0.f, 0.f};
#pragma unroll
        for (int nb = 0; nb < 4; nb++) o[qt][nb] = f32x4{0.f, 0.f, 0.f, 0.f};
    }

    const f16x4 ONES = {(_Float16)1.f, (_Float16)1.f, (_Float16)1.f, (_Float16)1.f};

    const int srw = tid >> 3, schk = tid & 7;
    const unsigned short* kg = K  + baseQK + (size_t)kt0 * 4096 + tid * 8;
    const unsigned short* vg = Vt + baseV + (size_t)kt0 * 64 + (size_t)srw * S_ + schk * 8;
    const int lb = srw * 64 + (schk ^ (srw & 7)) * 8;

    i32x4 kreg[2], vreg[2];
    kreg[0] = *(const i32x4*)(kg);
    kreg[1] = *(const i32x4*)(kg + 2048);
    vreg[0] = *(const i32x4*)(vg);
    vreg[1] = *(const i32x4*)(vg + 32 * S_);

    for (int it = 0; it < 8; it++) {
        __syncthreads();
        *(i32x4*)&Kl[lb]        = kreg[0];
        *(i32x4*)&Kl[lb + 2048] = kreg[1];
        *(i32x4*)&Vl[lb]        = vreg[0];
        *(i32x4*)&Vl[lb + 2048] = vreg[1];
        __syncthreads();

        if (it != 7) {
            const unsigned short* kn = kg + (it + 1) * 4096;
            const unsigned short* vn = vg + (it + 1) * 64;
            kreg[0] = *(const i32x4*)(kn);
            kreg[1] = *(const i32x4*)(kn + 2048);
            vreg[0] = *(const i32x4*)(vn);
            vreg[1] = *(const i32x4*)(vn + 32 * S_);
        }

        // S^T = K Q^T  (exp2 domain; KSCALE folded into K)
        f32x4 sa[2][4];
#pragma unroll
        for (int qt = 0; qt < 2; qt++)
#pragma unroll
            for (int kb = 0; kb < 4; kb++) sa[qt][kb] = f32x4{0.f, 0.f, 0.f, 0.f};
#pragma unroll
        for (int t = 0; t < 2; t++)
#pragma unroll
            for (int kb = 0; kb < 4; kb++) {
                bf16x8 kf = *(const bf16x8*)&Kl[(kb * 16 + r) * 64 + ((t * 4 + quad) ^ xk) * 8];
#pragma unroll
                for (int qt = 0; qt < 2; qt++)
                    sa[qt][kb] = __builtin_amdgcn_mfma_f32_16x16x32_bf16(
                        kf, qf[qt][t], sa[qt][kb], 0, 0, 0);
            }

        // p = exp2(s) -> f16 A-frags (layout already matches; cvt_pkrtz = RTZ)
        f16x4 pf[2][4];
#pragma unroll
        for (int qt = 0; qt < 2; qt++)
#pragma unroll
            for (int kb = 0; kb < 4; kb++) {
                float p0 = __builtin_amdgcn_exp2f(sa[qt][kb][0]);
                float p1 = __builtin_amdgcn_exp2f(sa[qt][kb][1]);
                float p2 = __builtin_amdgcn_exp2f(sa[qt][kb][2]);
                float p3 = __builtin_amdgcn_exp2f(sa[qt][kb][3]);
                union { f16x4 v; h16x2 h[2]; } u;
                u.h[0] = __builtin_amdgcn_cvt_pkrtz(p0, p1);
                u.h[1] = __builtin_amdgcn_cvt_pkrtz(p2, p3);
                pf[qt][kb] = u.v;
            }

        // O += P V  and  l += P 1   (fp16 MFMA, K=16 per kb)
#pragma unroll
        for (int kb = 0; kb < 4; kb++) {
#pragma unroll
            for (int nb = 0; nb < 4; nb++) {
                f16x4 vf = *(const f16x4*)&Vl[(nb * 16 + r) * 64 +
                                              ((kb * 2 + (quad >> 1)) ^ xk) * 8 + (quad & 1) * 4];
#pragma unroll
                for (int qt = 0; qt < 2; qt++)
                    o[qt][nb] = __builtin_amdgcn_mfma_f32_16x16x16f16(
                        pf[qt][kb], vf, o[qt][nb], 0, 0, 0);
            }
#pragma unroll
            for (int qt = 0; qt < 2; qt++)
                lacc[qt] = __builtin_amdgcn_mfma_f32_16x16x16f16(
                    pf[qt][kb], ONES, lacc[qt], 0, 0, 0);
        }
    }

    // epilogue: store UN-normalized partials (f16) + l (f32)
    unsigned short* Ob = On + (size_t)quarter * ONE_EL;
#pragma unroll
    for (int qt = 0; qt < 2; qt++)
#pragma unroll
        for (int i = 0; i < 4; i++) {
            int s = q0 + w * 32 + qt * 16 + quad * 4 + i;
            size_t row = (size_t)bh * S_ + s;
            if (r == 0) lbuf[quarter * LSTRIDE + row] = lacc[qt][i];
#pragma unroll
            for (int nb = 0; nb < 4; nb++) {
                union { _Float16 h; unsigned short u; } cv;
                cv.h = (_Float16)o[qt][nb][i];
                Ob[row * 64 + nb * 16 + r] = cv.u;
            }
        }
}

// ---------------------------------------------------------------------------
extern "C" void kernel_launch(void* const* d_in, const int* in_sizes, int n_in,
                              void* d_out, int out_size, void* d_ws, size_t ws_size,
                              hipStream_t stream) {
    const float* x     = (const float*)d_in[0];
    const float* w_in  = (const float*)d_in[1];
    const float* b_in  = (const float*)d_in[2];
    const float* w_out = (const float*)d_in[3];
    const float* b_out = (const float*)d_in[4];
    float* out = (float*)d_out;
    char* ws = (char*)d_ws;

    // workspace layout (bytes), ~61.3 MB (ws is ~268 MB per harness poison size):
    //   [0,        6291456)  xb (x bf16)
    //   [6291456,  9830400)  winT (bf16)   -> lbuf (f32, 786KB) after gemm_qkv
    //   [9830400, 11010048)  woutT (bf16)
    //   [11010048,17301504)  Q  (bf16)
    //   [17301504,23592960)  K  (bf16, scaled)
    //   [23592960,29884416)  Vt (fp16, written transposed by gemm_qkv)
    //   [36175872,61341696)  Onum: 4 contiguous f16 partials (4 x 6291456)
    unsigned short* xb    = (unsigned short*)(ws);
    unsigned short* winT  = (unsigned short*)(ws + 6291456);
    unsigned short* woutT = (unsigned short*)(ws + 9830400);
    unsigned short* QKV   = (unsigned short*)(ws + 11010048);
    unsigned short* On    = (unsigned short*)(ws + 36175872);

    const size_t one = (size_t)B_ * H_ * S_ * DH_;
    unsigned short* Vtbuf = QKV + 2 * one;
    float*          lbuf  = (float*)winT;             // winT dead after gemm_qkv

    prep_all<<<5376, 256, 0, stream>>>(x, w_in, w_out, xb, winT, woutT);

    gemm_qkv<<<dim3(N3_ / 96, M_ / 128), 256, 0, stream>>>(
        xb, winT, b_in, QKV, Vtbuf);

    attn_kernel<<<24 * 16 * 4, 256, 0, stream>>>(
        QKV, QKV + one, Vtbuf, On, lbuf);

    gemm_out<<<dim3(D_ / 64, M_ / 64), 256, 0, stream>>>(
        On, lbuf, woutT, b_out, out);
}

// Round 13
// 159.917 us; speedup vs baseline: 1.1268x; 1.1268x over previous
//
#include <hip/hip_runtime.h>
#include <stdint.h>

// Problem constants
#define B_   2
#define S_   2048
#define D_   768
#define H_   12
#define DH_  64
#define N3_  2304   // 3*D
#define M_   4096   // B*S

typedef __attribute__((ext_vector_type(8))) short    bf16x8;
typedef __attribute__((ext_vector_type(4))) float    f32x4;
typedef __attribute__((ext_vector_type(4))) int      i32x4;
typedef __attribute__((ext_vector_type(4))) unsigned short u16x4;
typedef _Float16 f16x4 __attribute__((ext_vector_type(4)));
typedef __fp16   h16x2 __attribute__((ext_vector_type(2)));   // cvt_pkrtz result type

// fold 1/sqrt(dh) * log2(e) into K at write time -> scores exit MFMA in exp2 domain
#define KSCALE 0.18033688011112042f
#define LSTRIDE (24 * S_)                 // l-buffer stride per split-K quarter
#define ONE_EL  ((size_t)24 * S_ * DH_)   // elements per Onum partial buffer

__device__ inline unsigned short f2bf(float f) {
    union { float f; unsigned u; } v; v.f = f;
    unsigned r = v.u + 0x7FFFu + ((v.u >> 16) & 1u);   // RNE
    return (unsigned short)(r >> 16);
}

// async 16B global -> LDS (DMA; LDS dest = wave-uniform base + lane*16)
__device__ inline void async_copy16(const void* g, void* l) {
    __builtin_amdgcn_global_load_lds((const __attribute__((address_space(1))) void*)g,
                                     (__attribute__((address_space(3))) void*)l, 16, 0, 0);
}

// ---------------------------------------------------------------------------
// Fused prep: x->bf16 (blocks 0..3071), w_in transpose (3072..4799),
// w_out transpose (4800..5375). Branch is block-uniform.
__global__ __launch_bounds__(256) void prep_all(
    const float* __restrict__ x, const float* __restrict__ w_in,
    const float* __restrict__ w_out,
    unsigned short* __restrict__ xb, unsigned short* __restrict__ winT,
    unsigned short* __restrict__ woutT)
{
    __shared__ unsigned short t[32][33];
    const int gid = blockIdx.x, tid = threadIdx.x;
    if (gid < 3072) {                      // cvt: 3072*256*4 = M*D elements
        int i = gid * 256 + tid;
        f32x4 v = *(const f32x4*)(x + (size_t)i * 4);
        u16x4 o;
        o.x = f2bf(v.x); o.y = f2bf(v.y); o.z = f2bf(v.z); o.w = f2bf(v.w);
        *(u16x4*)(xb + (size_t)i * 4) = o;
        return;
    }
    const float* src; unsigned short* dst; int R, C, bx, by;
    if (gid < 4800) { int b = gid - 3072; src = w_in;  dst = winT;  R = D_; C = N3_; bx = b % 72; by = b / 72; }
    else            { int b = gid - 4800; src = w_out; dst = woutT; R = D_; C = D_;  bx = b % 24; by = b / 24; }
    int c0 = bx * 32, r0 = by * 32, tx = tid & 31, ty = tid >> 5;
#pragma unroll
    for (int j = 0; j < 4; j++)
        t[ty + j * 8][tx] = f2bf(src[(size_t)(r0 + ty + j * 8) * C + c0 + tx]);
    __syncthreads();
#pragma unroll
    for (int j = 0; j < 4; j++)
        dst[(size_t)(c0 + ty + j * 8) * R + r0 + tx] = t[tx][ty + j * 8];
}

// ---------------------------------------------------------------------------
// GEMM1: QKV projection (unchanged from R11).
__global__ __launch_bounds__(256) void gemm_qkv(
    const unsigned short* __restrict__ A,
    const unsigned short* __restrict__ Bt,
    const float* __restrict__ bias,
    unsigned short* __restrict__ QK,
    unsigned short* __restrict__ Vt)
{
    __shared__ __align__(16) short Al[128 * 32];   // 8 KB
    __shared__ __align__(16) short Bl[96 * 32];    // 6 KB

    const int tid  = threadIdx.x;
    const int w    = tid >> 6;
    const int lane = tid & 63;
    const int r    = lane & 15;
    const int quad = lane >> 4;
    const int m0   = blockIdx.y * 128;
    const int n0   = blockIdx.x * 96;
    const int wm   = (w & 1) * 64;
    const int wn   = (w >> 1) * 48;
    const int K    = D_;

    f32x4 acc[4][3];
#pragma unroll
    for (int i = 0; i < 4; i++)
#pragma unroll
        for (int j = 0; j < 3; j++) acc[i][j] = f32x4{0.f, 0.f, 0.f, 0.f};

    const int c0 = tid, c1 = tid + 256;
    const size_t ga0 = (size_t)(m0 + (c0 >> 2)) * K + (c0 & 3) * 8;
    const size_t ga1 = (size_t)(m0 + (c1 >> 2)) * K + (c1 & 3) * 8;
    const size_t gb0 = (size_t)(n0 + (c0 >> 2)) * K + (c0 & 3) * 8;
    const size_t gb1 = (size_t)(n0 + (c1 >> 2)) * K + (c1 & 3) * 8;
    short* lA0 = &Al[(0 * 256 + w * 64) * 8];   // wave-uniform bases
    short* lA1 = &Al[(1 * 256 + w * 64) * 8];
    short* lB0 = &Bl[(0 * 256 + w * 64) * 8];
    short* lB1 = &Bl[(1 * 256 + w * 64) * 8];   // only waves 0,1

    for (int k0 = 0; k0 < K; k0 += 32) {
        __syncthreads();
        async_copy16(A  + ga0 + k0, lA0);
        async_copy16(A  + ga1 + k0, lA1);
        async_copy16(Bt + gb0 + k0, lB0);
        if (w < 2) async_copy16(Bt + gb1 + k0, lB1);
        __syncthreads();

        bf16x8 af[4], bf[3];
#pragma unroll
        for (int mi = 0; mi < 4; mi++)
            af[mi] = *(const bf16x8*)&Al[(wm + mi * 16 + r) * 32 + quad * 8];
#pragma unroll
        for (int ni = 0; ni < 3; ni++)
            bf[ni] = *(const bf16x8*)&Bl[(wn + ni * 16 + r) * 32 + quad * 8];
#pragma unroll
        for (int mi = 0; mi < 4; mi++)
#pragma unroll
            for (int ni = 0; ni < 3; ni++)
                acc[mi][ni] = __builtin_amdgcn_mfma_f32_16x16x32_bf16(
                    af[mi], bf[ni], acc[mi][ni], 0, 0, 0);
    }

    const size_t one = (size_t)B_ * H_ * S_ * DH_;
#pragma unroll
    for (int ni = 0; ni < 3; ni++) {
        int col  = n0 + wn + ni * 16 + r;        // 0..2303 (tiles never straddle parts)
        float bv = bias[col];
        int part = col / 768;                    // 0=q 1=k 2=v
        int cc   = col - part * 768;
        int h    = cc >> 6;
        int d    = cc & 63;
        if (part == 2) {
            // V^T direct: rows i=0..3 are consecutive s -> one 8B f16 pack
#pragma unroll
            for (int mi = 0; mi < 4; mi++) {
                int row0 = m0 + wm + mi * 16 + quad * 4;    // i=0; same b for i=0..3
                int b    = row0 >> 11;
                int s0   = row0 & 2047;
                u16x4 pk;
#pragma unroll
                for (int i = 0; i < 4; i++) {
                    union { _Float16 h; unsigned short s; } cv;
                    cv.h = (_Float16)(acc[mi][ni][i] + bv);
                    pk[i] = cv.s;
                }
                *(u16x4*)&Vt[(((size_t)(b * H_ + h)) * DH_ + d) * S_ + s0] = pk;
            }
        } else {
            float scl = (part == 1) ? KSCALE : 1.0f;
            unsigned short* dst = QK + (size_t)part * one;
#pragma unroll
            for (int mi = 0; mi < 4; mi++) {
#pragma unroll
                for (int i = 0; i < 4; i++) {
                    int row = m0 + wm + mi * 16 + quad * 4 + i;  // = b*S + s
                    int b   = row >> 11;
                    int s   = row & 2047;
                    dst[(((size_t)(b * H_ + h)) * S_ + s) * DH_ + d] =
                        f2bf((acc[mi][ni][i] + bv) * scl);
                }
            }
        }
    }
}

// ---------------------------------------------------------------------------
// GEMM2: output projection (R11 version — A is pre-combined bf16).
// Tile 64x64, BK=32 -> grid 12x64 = 768 blocks = exactly 3/CU.
__global__ __launch_bounds__(256) void gemm_out(
    const unsigned short* __restrict__ A,
    const unsigned short* __restrict__ Bt,
    const float* __restrict__ bias,
    float* __restrict__ Cf)
{
    __shared__ __align__(16) short Al[64 * 32];    // 4 KB
    __shared__ __align__(16) short Bl[64 * 32];    // 4 KB

    const int tid  = threadIdx.x;
    const int w    = tid >> 6;
    const int lane = tid & 63;
    const int r    = lane & 15;
    const int quad = lane >> 4;
    const int m0   = blockIdx.y * 64;
    const int n0   = blockIdx.x * 64;
    const int wm   = (w & 1) * 32;
    const int wn   = (w >> 1) * 32;
    const int K    = D_;
    const int N    = D_;

    f32x4 acc[2][2];
#pragma unroll
    for (int i = 0; i < 2; i++)
#pragma unroll
        for (int j = 0; j < 2; j++) acc[i][j] = f32x4{0.f, 0.f, 0.f, 0.f};

    const size_t ga = (size_t)(m0 + (tid >> 2)) * K + (tid & 3) * 8;
    const size_t gb = (size_t)(n0 + (tid >> 2)) * K + (tid & 3) * 8;
    short* lA = &Al[(w * 64) * 8];   // wave-uniform
    short* lB = &Bl[(w * 64) * 8];

    for (int k0 = 0; k0 < K; k0 += 32) {
        __syncthreads();
        async_copy16(A  + ga + k0, lA);
        async_copy16(Bt + gb + k0, lB);
        __syncthreads();

        bf16x8 af[2], bf[2];
#pragma unroll
        for (int mi = 0; mi < 2; mi++)
            af[mi] = *(const bf16x8*)&Al[(wm + mi * 16 + r) * 32 + quad * 8];
#pragma unroll
        for (int ni = 0; ni < 2; ni++)
            bf[ni] = *(const bf16x8*)&Bl[(wn + ni * 16 + r) * 32 + quad * 8];
#pragma unroll
        for (int mi = 0; mi < 2; mi++)
#pragma unroll
            for (int ni = 0; ni < 2; ni++)
                acc[mi][ni] = __builtin_amdgcn_mfma_f32_16x16x32_bf16(
                    af[mi], bf[ni], acc[mi][ni], 0, 0, 0);
    }

#pragma unroll
    for (int ni = 0; ni < 2; ni++) {
        int col  = n0 + wn + ni * 16 + r;
        float bv = bias[col];
#pragma unroll
        for (int mi = 0; mi < 2; mi++) {
#pragma unroll
            for (int i = 0; i < 4; i++) {
                int row = m0 + wm + mi * 16 + quad * 4 + i;
                Cf[(size_t)row * N + col] = acc[mi][ni][i] + bv;
            }
        }
    }
}

// ---------------------------------------------------------------------------
// Flash attention v7: S^T scheme + split-K x4 (8 kt-iters/block).
// Grid = 24*16*4 = 1536 = 6 blocks/CU -> 24 waves/CU.
// Partials: Onum f16 [quarter][bh][s][64] (contiguous), l f32 [quarter][bh*s].
__global__ __launch_bounds__(256) void attn_kernel(
    const unsigned short* __restrict__ Q,
    const unsigned short* __restrict__ K,
    const unsigned short* __restrict__ Vt,
    unsigned short* __restrict__ On,
    float* __restrict__ lbuf)
{
    __shared__ __align__(16) short Kl[64 * 64];      // [key][dh], chunk^=(row&7)
    __shared__ __align__(16) short Vl[64 * 64];      // [dh][key], chunk^=(row&7)

    const int tid  = threadIdx.x;
    const int w    = tid >> 6;
    const int lane = tid & 63;
    const int r    = lane & 15;
    const int quad = lane >> 4;
    const int xk   = r & 7;
    const int bid  = blockIdx.x;
    const int bh   = bid % 24;            // head-major -> L2 locality
    const int t2   = bid / 24;            // 0..63
    const int qb   = t2 & 15;
    const int quarter = t2 >> 4;          // 0..3
    const size_t baseQK = (size_t)bh * S_ * DH_;
    const size_t baseV  = (size_t)bh * DH_ * S_;
    const int q0   = qb * 128;
    const int kt0  = quarter * 8;

    bf16x8 qf[2][2];
#pragma unroll
    for (int qt = 0; qt < 2; qt++) {
        const unsigned short* qp =
            Q + baseQK + (size_t)(q0 + w * 32 + qt * 16 + r) * DH_ + quad * 8;
        qf[qt][0] = *(const bf16x8*)(qp);
        qf[qt][1] = *(const bf16x8*)(qp + 32);
    }

    f32x4 o[2][4];
    f32x4 lacc[2];
#pragma unroll
    for (int qt = 0; qt < 2; qt++) {
        lacc[qt] = f32x4{0.f, 0.f, 0.f, 0.f};
#pragma unroll
        for (int nb = 0; nb < 4; nb++) o[qt][nb] = f32x4{0.f, 0.f, 0.f, 0.f};
    }

    const f16x4 ONES = {(_Float16)1.f, (_Float16)1.f, (_Float16)1.f, (_Float16)1.f};

    const int srw = tid >> 3, schk = tid & 7;
    const unsigned short* kg = K  + baseQK + (size_t)kt0 * 4096 + tid * 8;
    const unsigned short* vg = Vt + baseV + (size_t)kt0 * 64 + (size_t)srw * S_ + schk * 8;
    const int lb = srw * 64 + (schk ^ (srw & 7)) * 8;

    i32x4 kreg[2], vreg[2];
    kreg[0] = *(const i32x4*)(kg);
    kreg[1] = *(const i32x4*)(kg + 2048);
    vreg[0] = *(const i32x4*)(vg);
    vreg[1] = *(const i32x4*)(vg + 32 * S_);

    for (int it = 0; it < 8; it++) {
        __syncthreads();
        *(i32x4*)&Kl[lb]        = kreg[0];
        *(i32x4*)&Kl[lb + 2048] = kreg[1];
        *(i32x4*)&Vl[lb]        = vreg[0];
        *(i32x4*)&Vl[lb + 2048] = vreg[1];
        __syncthreads();

        if (it != 7) {
            const unsigned short* kn = kg + (it + 1) * 4096;
            const unsigned short* vn = vg + (it + 1) * 64;
            kreg[0] = *(const i32x4*)(kn);
            kreg[1] = *(const i32x4*)(kn + 2048);
            vreg[0] = *(const i32x4*)(vn);
            vreg[1] = *(const i32x4*)(vn + 32 * S_);
        }

        // S^T = K Q^T  (exp2 domain; KSCALE folded into K)
        f32x4 sa[2][4];
#pragma unroll
        for (int qt = 0; qt < 2; qt++)
#pragma unroll
            for (int kb = 0; kb < 4; kb++) sa[qt][kb] = f32x4{0.f, 0.f, 0.f, 0.f};
#pragma unroll
        for (int t = 0; t < 2; t++)
#pragma unroll
            for (int kb = 0; kb < 4; kb++) {
                bf16x8 kf = *(const bf16x8*)&Kl[(kb * 16 + r) * 64 + ((t * 4 + quad) ^ xk) * 8];
#pragma unroll
                for (int qt = 0; qt < 2; qt++)
                    sa[qt][kb] = __builtin_amdgcn_mfma_f32_16x16x32_bf16(
                        kf, qf[qt][t], sa[qt][kb], 0, 0, 0);
            }

        // p = exp2(s) -> f16 A-frags (layout already matches; cvt_pkrtz = RTZ)
        f16x4 pf[2][4];
#pragma unroll
        for (int qt = 0; qt < 2; qt++)
#pragma unroll
            for (int kb = 0; kb < 4; kb++) {
                float p0 = __builtin_amdgcn_exp2f(sa[qt][kb][0]);
                float p1 = __builtin_amdgcn_exp2f(sa[qt][kb][1]);
                float p2 = __builtin_amdgcn_exp2f(sa[qt][kb][2]);
                float p3 = __builtin_amdgcn_exp2f(sa[qt][kb][3]);
                union { f16x4 v; h16x2 h[2]; } u;
                u.h[0] = __builtin_amdgcn_cvt_pkrtz(p0, p1);
                u.h[1] = __builtin_amdgcn_cvt_pkrtz(p2, p3);
                pf[qt][kb] = u.v;
            }

        // O += P V  and  l += P 1   (fp16 MFMA, K=16 per kb)
#pragma unroll
        for (int kb = 0; kb < 4; kb++) {
#pragma unroll
            for (int nb = 0; nb < 4; nb++) {
                f16x4 vf = *(const f16x4*)&Vl[(nb * 16 + r) * 64 +
                                              ((kb * 2 + (quad >> 1)) ^ xk) * 8 + (quad & 1) * 4];
#pragma unroll
                for (int qt = 0; qt < 2; qt++)
                    o[qt][nb] = __builtin_amdgcn_mfma_f32_16x16x16f16(
                        pf[qt][kb], vf, o[qt][nb], 0, 0, 0);
            }
#pragma unroll
            for (int qt = 0; qt < 2; qt++)
                lacc[qt] = __builtin_amdgcn_mfma_f32_16x16x16f16(
                    pf[qt][kb], ONES, lacc[qt], 0, 0, 0);
        }
    }

    // epilogue: store UN-normalized partials (f16) + l (f32)
    unsigned short* Ob = On + (size_t)quarter * ONE_EL;
#pragma unroll
    for (int qt = 0; qt < 2; qt++)
#pragma unroll
        for (int i = 0; i < 4; i++) {
            int s = q0 + w * 32 + qt * 16 + quad * 4 + i;
            size_t row = (size_t)bh * S_ + s;
            if (r == 0) lbuf[quarter * LSTRIDE + row] = lacc[qt][i];
#pragma unroll
            for (int nb = 0; nb < 4; nb++) {
                union { _Float16 h; unsigned short u; } cv;
                cv.h = (_Float16)o[qt][nb][i];
                Ob[row * 64 + nb * 16 + r] = cv.u;
            }
        }
}

// Combine 4 split-K partials: out = sum(Oi)/sum(li), bf16 [B][S][D] merged.
// Fully coalesced 16B loads/stores; writes A once so gemm_out streams bf16.
__global__ void combine_attn(const unsigned short* __restrict__ On,
                             const float* __restrict__ lbuf,
                             unsigned short* __restrict__ Out)
{
    int g   = blockIdx.x * 256 + threadIdx.x;   // 0 .. 393215
    int hd8 = g % 96;                           // 12 heads * 8 chunks
    int bs  = g / 96;                           // b*2048 + s
    int h   = hd8 >> 3;
    int d8  = (hd8 & 7) * 8;
    size_t row = ((size_t)((bs >> 11) * H_ + h)) * S_ + (bs & 2047);
    float inv = 1.0f / (lbuf[row] + lbuf[LSTRIDE + row] +
                        lbuf[2 * LSTRIDE + row] + lbuf[3 * LSTRIDE + row]);
    size_t ob = row * 64 + d8;
    i32x4 a0 = *(const i32x4*)&On[ob];
    i32x4 a1 = *(const i32x4*)&On[ob + ONE_EL];
    i32x4 a2 = *(const i32x4*)&On[ob + 2 * ONE_EL];
    i32x4 a3 = *(const i32x4*)&On[ob + 3 * ONE_EL];
    const _Float16* f0 = (const _Float16*)&a0;
    const _Float16* f1 = (const _Float16*)&a1;
    const _Float16* f2 = (const _Float16*)&a2;
    const _Float16* f3 = (const _Float16*)&a3;
    unsigned short tmp[8];
#pragma unroll
    for (int j = 0; j < 8; j++)
        tmp[j] = f2bf(((float)f0[j] + (float)f1[j] + (float)f2[j] + (float)f3[j]) * inv);
    *(i32x4*)&Out[(size_t)bs * D_ + h * 64 + d8] = *(const i32x4*)tmp;
}

// ---------------------------------------------------------------------------
extern "C" void kernel_launch(void* const* d_in, const int* in_sizes, int n_in,
                              void* d_out, int out_size, void* d_ws, size_t ws_size,
                              hipStream_t stream) {
    const float* x     = (const float*)d_in[0];
    const float* w_in  = (const float*)d_in[1];
    const float* b_in  = (const float*)d_in[2];
    const float* w_out = (const float*)d_in[3];
    const float* b_out = (const float*)d_in[4];
    float* out = (float*)d_out;
    char* ws = (char*)d_ws;

    // workspace layout (bytes), ~61.3 MB:
    //   [0,        6291456)  xb (x bf16)
    //   [6291456,  9830400)  winT (bf16)   -> lbuf (f32, 786KB) after gemm_qkv
    //   [9830400, 11010048)  woutT (bf16)
    //   [11010048,17301504)  Q  (bf16)     -> attn output (bf16) after attn
    //   [17301504,23592960)  K  (bf16, scaled)
    //   [23592960,29884416)  Vt (fp16, written transposed by gemm_qkv)
    //   [36175872,61341696)  Onum: 4 contiguous f16 partials (4 x 6291456)
    unsigned short* xb    = (unsigned short*)(ws);
    unsigned short* winT  = (unsigned short*)(ws + 6291456);
    unsigned short* woutT = (unsigned short*)(ws + 9830400);
    unsigned short* QKV   = (unsigned short*)(ws + 11010048);
    unsigned short* On    = (unsigned short*)(ws + 36175872);

    const size_t one = (size_t)B_ * H_ * S_ * DH_;
    unsigned short* Vtbuf = QKV + 2 * one;
    float*          lbuf  = (float*)winT;             // winT dead after gemm_qkv
    unsigned short* attnO = QKV;                      // Q slot, dead after attn

    prep_all<<<5376, 256, 0, stream>>>(x, w_in, w_out, xb, winT, woutT);

    gemm_qkv<<<dim3(N3_ / 96, M_ / 128), 256, 0, stream>>>(
        xb, winT, b_in, QKV, Vtbuf);

    attn_kernel<<<24 * 16 * 4, 256, 0, stream>>>(
        QKV, QKV + one, Vtbuf, On, lbuf);

    combine_attn<<<1536, 256, 0, stream>>>(On, lbuf, attnO);

    gemm_out<<<dim3(D_ / 64, M_ / 64), 256, 0, stream>>>(
        attnO, woutT, b_out, out);
}

// Round 14
// 157.825 us; speedup vs baseline: 1.1417x; 1.0133x over previous
//
#include <hip/hip_runtime.h>
#include <stdint.h>

// Problem constants
#define B_   2
#define S_   2048
#define D_   768
#define H_   12
#define DH_  64
#define N3_  2304   // 3*D
#define M_   4096   // B*S

typedef __attribute__((ext_vector_type(8))) short    bf16x8;
typedef __attribute__((ext_vector_type(4))) float    f32x4;
typedef __attribute__((ext_vector_type(4))) int      i32x4;
typedef __attribute__((ext_vector_type(4))) unsigned short u16x4;
typedef _Float16 f16x4 __attribute__((ext_vector_type(4)));
typedef __fp16   h16x2 __attribute__((ext_vector_type(2)));   // cvt_pkrtz result type

// fold 1/sqrt(dh) * log2(e) into K at write time -> scores exit MFMA in exp2 domain
#define KSCALE 0.18033688011112042f
#define LSTRIDE (24 * S_)                 // l-buffer stride per split-K half
#define ONE_EL  ((size_t)24 * S_ * DH_)   // elements per Onum partial buffer

__device__ inline unsigned short f2bf(float f) {
    union { float f; unsigned u; } v; v.f = f;
    unsigned r = v.u + 0x7FFFu + ((v.u >> 16) & 1u);   // RNE
    return (unsigned short)(r >> 16);
}

// async 16B global -> LDS (DMA; LDS dest = wave-uniform base + lane*16)
__device__ inline void async_copy16(const void* g, void* l) {
    __builtin_amdgcn_global_load_lds((const __attribute__((address_space(1))) void*)g,
                                     (__attribute__((address_space(3))) void*)l, 16, 0, 0);
}

// ---------------------------------------------------------------------------
// Fused prep: x->bf16 (blocks 0..3071), w_in transpose (3072..4799),
// w_out transpose (4800..5375). Branch is block-uniform.
__global__ __launch_bounds__(256) void prep_all(
    const float* __restrict__ x, const float* __restrict__ w_in,
    const float* __restrict__ w_out,
    unsigned short* __restrict__ xb, unsigned short* __restrict__ winT,
    unsigned short* __restrict__ woutT)
{
    __shared__ unsigned short t[32][33];
    const int gid = blockIdx.x, tid = threadIdx.x;
    if (gid < 3072) {                      // cvt: 3072*256*4 = M*D elements
        int i = gid * 256 + tid;
        f32x4 v = *(const f32x4*)(x + (size_t)i * 4);
        u16x4 o;
        o.x = f2bf(v.x); o.y = f2bf(v.y); o.z = f2bf(v.z); o.w = f2bf(v.w);
        *(u16x4*)(xb + (size_t)i * 4) = o;
        return;
    }
    const float* src; unsigned short* dst; int R, C, bx, by;
    if (gid < 4800) { int b = gid - 3072; src = w_in;  dst = winT;  R = D_; C = N3_; bx = b % 72; by = b / 72; }
    else            { int b = gid - 4800; src = w_out; dst = woutT; R = D_; C = D_;  bx = b % 24; by = b / 24; }
    int c0 = bx * 32, r0 = by * 32, tx = tid & 31, ty = tid >> 5;
#pragma unroll
    for (int j = 0; j < 4; j++)
        t[ty + j * 8][tx] = f2bf(src[(size_t)(r0 + ty + j * 8) * C + c0 + tx]);
    __syncthreads();
#pragma unroll
    for (int j = 0; j < 4; j++)
        dst[(size_t)(c0 + ty + j * 8) * R + r0 + tx] = t[tx][ty + j * 8];
}

// ---------------------------------------------------------------------------
// GEMM1: QKV projection. Tile 128x96, 1-D grid 768 with XCD-affinity swizzle:
// all 24 n-blocks sharing an A m-stripe have identical bid%8 -> same XCD ->
// A-stripe (786KB) stays L2-resident across its 24 consumers.
__global__ __launch_bounds__(256) void gemm_qkv(
    const unsigned short* __restrict__ A,
    const unsigned short* __restrict__ Bt,
    const float* __restrict__ bias,
    unsigned short* __restrict__ QK,
    unsigned short* __restrict__ Vt)
{
    __shared__ __align__(16) short Al[128 * 32];   // 8 KB
    __shared__ __align__(16) short Bl[96 * 32];    // 6 KB

    const int tid  = threadIdx.x;
    const int w    = tid >> 6;
    const int lane = tid & 63;
    const int r    = lane & 15;
    const int quad = lane >> 4;
    // swizzle: xcd = bid&7; m-tile = xcd + 8*(rest/24); n-tile = rest%24
    const int bid  = blockIdx.x;
    const int rest = bid >> 3;
    const int m0   = ((bid & 7) + 8 * (rest / 24)) * 128;
    const int n0   = (rest % 24) * 96;
    const int wm   = (w & 1) * 64;
    const int wn   = (w >> 1) * 48;
    const int K    = D_;

    f32x4 acc[4][3];
#pragma unroll
    for (int i = 0; i < 4; i++)
#pragma unroll
        for (int j = 0; j < 3; j++) acc[i][j] = f32x4{0.f, 0.f, 0.f, 0.f};

    const int c0 = tid, c1 = tid + 256;
    const size_t ga0 = (size_t)(m0 + (c0 >> 2)) * K + (c0 & 3) * 8;
    const size_t ga1 = (size_t)(m0 + (c1 >> 2)) * K + (c1 & 3) * 8;
    const size_t gb0 = (size_t)(n0 + (c0 >> 2)) * K + (c0 & 3) * 8;
    const size_t gb1 = (size_t)(n0 + (c1 >> 2)) * K + (c1 & 3) * 8;
    short* lA0 = &Al[(0 * 256 + w * 64) * 8];   // wave-uniform bases
    short* lA1 = &Al[(1 * 256 + w * 64) * 8];
    short* lB0 = &Bl[(0 * 256 + w * 64) * 8];
    short* lB1 = &Bl[(1 * 256 + w * 64) * 8];   // only waves 0,1

    for (int k0 = 0; k0 < K; k0 += 32) {
        __syncthreads();
        async_copy16(A  + ga0 + k0, lA0);
        async_copy16(A  + ga1 + k0, lA1);
        async_copy16(Bt + gb0 + k0, lB0);
        if (w < 2) async_copy16(Bt + gb1 + k0, lB1);
        __syncthreads();

        bf16x8 af[4], bf[3];
#pragma unroll
        for (int mi = 0; mi < 4; mi++)
            af[mi] = *(const bf16x8*)&Al[(wm + mi * 16 + r) * 32 + quad * 8];
#pragma unroll
        for (int ni = 0; ni < 3; ni++)
            bf[ni] = *(const bf16x8*)&Bl[(wn + ni * 16 + r) * 32 + quad * 8];
#pragma unroll
        for (int mi = 0; mi < 4; mi++)
#pragma unroll
            for (int ni = 0; ni < 3; ni++)
                acc[mi][ni] = __builtin_amdgcn_mfma_f32_16x16x32_bf16(
                    af[mi], bf[ni], acc[mi][ni], 0, 0, 0);
    }

    const size_t one = (size_t)B_ * H_ * S_ * DH_;
#pragma unroll
    for (int ni = 0; ni < 3; ni++) {
        int col  = n0 + wn + ni * 16 + r;        // 0..2303 (tiles never straddle parts)
        float bv = bias[col];
        int part = col / 768;                    // 0=q 1=k 2=v
        int cc   = col - part * 768;
        int h    = cc >> 6;
        int d    = cc & 63;
        if (part == 2) {
            // V^T direct: rows i=0..3 are consecutive s -> one 8B f16 pack
#pragma unroll
            for (int mi = 0; mi < 4; mi++) {
                int row0 = m0 + wm + mi * 16 + quad * 4;    // i=0; same b for i=0..3
                int b    = row0 >> 11;
                int s0   = row0 & 2047;
                u16x4 pk;
#pragma unroll
                for (int i = 0; i < 4; i++) {
                    union { _Float16 h; unsigned short s; } cv;
                    cv.h = (_Float16)(acc[mi][ni][i] + bv);
                    pk[i] = cv.s;
                }
                *(u16x4*)&Vt[(((size_t)(b * H_ + h)) * DH_ + d) * S_ + s0] = pk;
            }
        } else {
            float scl = (part == 1) ? KSCALE : 1.0f;
            unsigned short* dst = QK + (size_t)part * one;
#pragma unroll
            for (int mi = 0; mi < 4; mi++) {
#pragma unroll
                for (int i = 0; i < 4; i++) {
                    int row = m0 + wm + mi * 16 + quad * 4 + i;  // = b*S + s
                    int b   = row >> 11;
                    int s   = row & 2047;
                    dst[(((size_t)(b * H_ + h)) * S_ + s) * DH_ + d] =
                        f2bf((acc[mi][ni][i] + bv) * scl);
                }
            }
        }
    }
}

// ---------------------------------------------------------------------------
// GEMM2: output projection. Tile 64x64, 1-D grid 768 with the same XCD swizzle
// (12 n-blocks per m-stripe pinned to one XCD; 8x96KB A + 1.2MB B per L2).
__global__ __launch_bounds__(256) void gemm_out(
    const unsigned short* __restrict__ A,
    const unsigned short* __restrict__ Bt,
    const float* __restrict__ bias,
    float* __restrict__ Cf)
{
    __shared__ __align__(16) short Al[64 * 32];    // 4 KB
    __shared__ __align__(16) short Bl[64 * 32];    // 4 KB

    const int tid  = threadIdx.x;
    const int w    = tid >> 6;
    const int lane = tid & 63;
    const int r    = lane & 15;
    const int quad = lane >> 4;
    const int bid  = blockIdx.x;
    const int rest = bid >> 3;
    const int m0   = ((bid & 7) + 8 * (rest / 12)) * 64;
    const int n0   = (rest % 12) * 64;
    const int wm   = (w & 1) * 32;
    const int wn   = (w >> 1) * 32;
    const int K    = D_;
    const int N    = D_;

    f32x4 acc[2][2];
#pragma unroll
    for (int i = 0; i < 2; i++)
#pragma unroll
        for (int j = 0; j < 2; j++) acc[i][j] = f32x4{0.f, 0.f, 0.f, 0.f};

    const size_t ga = (size_t)(m0 + (tid >> 2)) * K + (tid & 3) * 8;
    const size_t gb = (size_t)(n0 + (tid >> 2)) * K + (tid & 3) * 8;
    short* lA = &Al[(w * 64) * 8];   // wave-uniform
    short* lB = &Bl[(w * 64) * 8];

    for (int k0 = 0; k0 < K; k0 += 32) {
        __syncthreads();
        async_copy16(A  + ga + k0, lA);
        async_copy16(Bt + gb + k0, lB);
        __syncthreads();

        bf16x8 af[2], bf[2];
#pragma unroll
        for (int mi = 0; mi < 2; mi++)
            af[mi] = *(const bf16x8*)&Al[(wm + mi * 16 + r) * 32 + quad * 8];
#pragma unroll
        for (int ni = 0; ni < 2; ni++)
            bf[ni] = *(const bf16x8*)&Bl[(wn + ni * 16 + r) * 32 + quad * 8];
#pragma unroll
        for (int mi = 0; mi < 2; mi++)
#pragma unroll
            for (int ni = 0; ni < 2; ni++)
                acc[mi][ni] = __builtin_amdgcn_mfma_f32_16x16x32_bf16(
                    af[mi], bf[ni], acc[mi][ni], 0, 0, 0);
    }

#pragma unroll
    for (int ni = 0; ni < 2; ni++) {
        int col  = n0 + wn + ni * 16 + r;
        float bv = bias[col];
#pragma unroll
        for (int mi = 0; mi < 2; mi++) {
#pragma unroll
            for (int i = 0; i < 4; i++) {
                int row = m0 + wm + mi * 16 + quad * 4 + i;
                Cf[(size_t)row * N + col] = acc[mi][ni][i] + bv;
            }
        }
    }
}

// ---------------------------------------------------------------------------
// Flash attention v6 (R10-proven): S^T scheme + split-K x2 (16 kt-iters/block).
// Grid = 24*16*2 = 768 = exactly 3 blocks/CU.
// Partials: Onum f16 [half][bh][s][64] (contiguous), l f32 [half][bh*s].
__global__ __launch_bounds__(256) void attn_kernel(
    const unsigned short* __restrict__ Q,
    const unsigned short* __restrict__ K,
    const unsigned short* __restrict__ Vt,
    unsigned short* __restrict__ On,
    float* __restrict__ lbuf)
{
    __shared__ __align__(16) short Kl[64 * 64];      // [key][dh], chunk^=(row&7)
    __shared__ __align__(16) short Vl[64 * 64];      // [dh][key], chunk^=(row&7)

    const int tid  = threadIdx.x;
    const int w    = tid >> 6;
    const int lane = tid & 63;
    const int r    = lane & 15;
    const int quad = lane >> 4;
    const int xk   = r & 7;
    const int bid  = blockIdx.x;
    const int bh   = bid % 24;            // head-major -> L2 locality
    const int t2   = bid / 24;            // 0..31
    const int qb   = t2 & 15;
    const int half = t2 >> 4;
    const size_t baseQK = (size_t)bh * S_ * DH_;
    const size_t baseV  = (size_t)bh * DH_ * S_;
    const int q0   = qb * 128;
    const int kt0  = half * 16;

    bf16x8 qf[2][2];
#pragma unroll
    for (int qt = 0; qt < 2; qt++) {
        const unsigned short* qp =
            Q + baseQK + (size_t)(q0 + w * 32 + qt * 16 + r) * DH_ + quad * 8;
        qf[qt][0] = *(const bf16x8*)(qp);
        qf[qt][1] = *(const bf16x8*)(qp + 32);
    }

    f32x4 o[2][4];
    f32x4 lacc[2];
#pragma unroll
    for (int qt = 0; qt < 2; qt++) {
        lacc[qt] = f32x4{0.f, 0.f, 0.f, 0.f};
#pragma unroll
        for (int nb = 0; nb < 4; nb++) o[qt][nb] = f32x4{0.f, 0.f, 0.f, 0.f};
    }

    const f16x4 ONES = {(_Float16)1.f, (_Float16)1.f, (_Float16)1.f, (_Float16)1.f};

    const int srw = tid >> 3, schk = tid & 7;
    const unsigned short* kg = K  + baseQK + (size_t)kt0 * 4096 + tid * 8;
    const unsigned short* vg = Vt + baseV + (size_t)kt0 * 64 + (size_t)srw * S_ + schk * 8;
    const int lb = srw * 64 + (schk ^ (srw & 7)) * 8;

    i32x4 kreg[2], vreg[2];
    kreg[0] = *(const i32x4*)(kg);
    kreg[1] = *(const i32x4*)(kg + 2048);
    vreg[0] = *(const i32x4*)(vg);
    vreg[1] = *(const i32x4*)(vg + 32 * S_);

    for (int it = 0; it < 16; it++) {
        __syncthreads();
        *(i32x4*)&Kl[lb]        = kreg[0];
        *(i32x4*)&Kl[lb + 2048] = kreg[1];
        *(i32x4*)&Vl[lb]        = vreg[0];
        *(i32x4*)&Vl[lb + 2048] = vreg[1];
        __syncthreads();

        if (it != 15) {
            const unsigned short* kn = kg + (it + 1) * 4096;
            const unsigned short* vn = vg + (it + 1) * 64;
            kreg[0] = *(const i32x4*)(kn);
            kreg[1] = *(const i32x4*)(kn + 2048);
            vreg[0] = *(const i32x4*)(vn);
            vreg[1] = *(const i32x4*)(vn + 32 * S_);
        }

        // S^T = K Q^T  (exp2 domain; KSCALE folded into K)
        f32x4 sa[2][4];
#pragma unroll
        for (int qt = 0; qt < 2; qt++)
#pragma unroll
            for (int kb = 0; kb < 4; kb++) sa[qt][kb] = f32x4{0.f, 0.f, 0.f, 0.f};
#pragma unroll
        for (int t = 0; t < 2; t++)
#pragma unroll
            for (int kb = 0; kb < 4; kb++) {
                bf16x8 kf = *(const bf16x8*)&Kl[(kb * 16 + r) * 64 + ((t * 4 + quad) ^ xk) * 8];
#pragma unroll
                for (int qt = 0; qt < 2; qt++)
                    sa[qt][kb] = __builtin_amdgcn_mfma_f32_16x16x32_bf16(
                        kf, qf[qt][t], sa[qt][kb], 0, 0, 0);
            }

        // p = exp2(s) -> f16 A-frags (layout already matches; cvt_pkrtz = RTZ)
        f16x4 pf[2][4];
#pragma unroll
        for (int qt = 0; qt < 2; qt++)
#pragma unroll
            for (int kb = 0; kb < 4; kb++) {
                float p0 = __builtin_amdgcn_exp2f(sa[qt][kb][0]);
                float p1 = __builtin_amdgcn_exp2f(sa[qt][kb][1]);
                float p2 = __builtin_amdgcn_exp2f(sa[qt][kb][2]);
                float p3 = __builtin_amdgcn_exp2f(sa[qt][kb][3]);
                union { f16x4 v; h16x2 h[2]; } u;
                u.h[0] = __builtin_amdgcn_cvt_pkrtz(p0, p1);
                u.h[1] = __builtin_amdgcn_cvt_pkrtz(p2, p3);
                pf[qt][kb] = u.v;
            }

        // O += P V  and  l += P 1   (fp16 MFMA, K=16 per kb)
#pragma unroll
        for (int kb = 0; kb < 4; kb++) {
#pragma unroll
            for (int nb = 0; nb < 4; nb++) {
                f16x4 vf = *(const f16x4*)&Vl[(nb * 16 + r) * 64 +
                                              ((kb * 2 + (quad >> 1)) ^ xk) * 8 + (quad & 1) * 4];
#pragma unroll
                for (int qt = 0; qt < 2; qt++)
                    o[qt][nb] = __builtin_amdgcn_mfma_f32_16x16x16f16(
                        pf[qt][kb], vf, o[qt][nb], 0, 0, 0);
            }
#pragma unroll
            for (int qt = 0; qt < 2; qt++)
                lacc[qt] = __builtin_amdgcn_mfma_f32_16x16x16f16(
                    pf[qt][kb], ONES, lacc[qt], 0, 0, 0);
        }
    }

    // epilogue: store UN-normalized partials (f16) + l (f32)
    unsigned short* Ob = On + (size_t)half * ONE_EL;
#pragma unroll
    for (int qt = 0; qt < 2; qt++)
#pragma unroll
        for (int i = 0; i < 4; i++) {
            int s = q0 + w * 32 + qt * 16 + quad * 4 + i;
            size_t row = (size_t)bh * S_ + s;
            if (r == 0) lbuf[half * LSTRIDE + row] = lacc[qt][i];
#pragma unroll
            for (int nb = 0; nb < 4; nb++) {
                union { _Float16 h; unsigned short u; } cv;
                cv.h = (_Float16)o[qt][nb][i];
                Ob[row * 64 + nb * 16 + r] = cv.u;
            }
        }
}

// Combine 2 split-K partials: out = (O0+O1)/(l0+l1), bf16 [B][S][D] merged.
__global__ void combine_attn(const unsigned short* __restrict__ On,
                             const float* __restrict__ lbuf,
                             unsigned short* __restrict__ Out)
{
    int g   = blockIdx.x * 256 + threadIdx.x;   // 0 .. 393215
    int hd8 = g % 96;                           // 12 heads * 8 chunks
    int bs  = g / 96;                           // b*2048 + s
    int h   = hd8 >> 3;
    int d8  = (hd8 & 7) * 8;
    size_t row = ((size_t)((bs >> 11) * H_ + h)) * S_ + (bs & 2047);
    float inv = 1.0f / (lbuf[row] + lbuf[LSTRIDE + row]);
    size_t ob = row * 64 + d8;
    i32x4 a0 = *(const i32x4*)&On[ob];
    i32x4 a1 = *(const i32x4*)&On[ob + ONE_EL];
    const _Float16* f0 = (const _Float16*)&a0;
    const _Float16* f1 = (const _Float16*)&a1;
    unsigned short tmp[8];
#pragma unroll
    for (int j = 0; j < 8; j++)
        tmp[j] = f2bf(((float)f0[j] + (float)f1[j]) * inv);
    *(i32x4*)&Out[(size_t)bs * D_ + h * 64 + d8] = *(const i32x4*)tmp;
}

// ---------------------------------------------------------------------------
extern "C" void kernel_launch(void* const* d_in, const int* in_sizes, int n_in,
                              void* d_out, int out_size, void* d_ws, size_t ws_size,
                              hipStream_t stream) {
    const float* x     = (const float*)d_in[0];
    const float* w_in  = (const float*)d_in[1];
    const float* b_in  = (const float*)d_in[2];
    const float* w_out = (const float*)d_in[3];
    const float* b_out = (const float*)d_in[4];
    float* out = (float*)d_out;
    char* ws = (char*)d_ws;

    // workspace layout (bytes), ~48.8 MB:
    //   [0,        6291456)  xb (x bf16)
    //   [6291456,  9830400)  winT (bf16)   -> lbuf (f32, 393KB) after gemm_qkv
    //   [9830400, 11010048)  woutT (bf16)
    //   [11010048,17301504)  Q  (bf16)     -> attn output (bf16) after attn
    //   [17301504,23592960)  K  (bf16, scaled)
    //   [23592960,29884416)  Vt (fp16, written transposed by gemm_qkv)
    //   [36175872,48758784)  Onum: 2 contiguous f16 partials (2 x 6291456)
    unsigned short* xb    = (unsigned short*)(ws);
    unsigned short* winT  = (unsigned short*)(ws + 6291456);
    unsigned short* woutT = (unsigned short*)(ws + 9830400);
    unsigned short* QKV   = (unsigned short*)(ws + 11010048);
    unsigned short* On    = (unsigned short*)(ws + 36175872);

    const size_t one = (size_t)B_ * H_ * S_ * DH_;
    unsigned short* Vtbuf = QKV + 2 * one;
    float*          lbuf  = (float*)winT;             // winT dead after gemm_qkv
    unsigned short* attnO = QKV;                      // Q slot, dead after attn

    prep_all<<<5376, 256, 0, stream>>>(x, w_in, w_out, xb, winT, woutT);

    gemm_qkv<<<768, 256, 0, stream>>>(xb, winT, b_in, QKV, Vtbuf);

    attn_kernel<<<24 * 16 * 2, 256, 0, stream>>>(
        QKV, QKV + one, Vtbuf, On, lbuf);

    combine_attn<<<1536, 256, 0, stream>>>(On, lbuf, attnO);

    gemm_out<<<768, 256, 0, stream>>>(attnO, woutT, b_out, out);
}